// Round 11
// baseline (239.458 us; speedup 1.0000x reference)
//
#include <hip/hip_runtime.h>

#define N_NODES  100000
#define N_EDGES  1200000
#define N_GRAPHS 1024

#define BSH    9                     // 512-node buckets
#define BNODES 512
#define NBUCK  196                   // ceil(100000/512)
#define FBLK   512                   // cnt/fill blocks
#define CHUNK  ((N_EDGES + FBLK - 1) / FBLK)   // 2344
#define ENC_BLOCKS 1563              // ceil(6250 enc-waves / 4)

// bf16 pack/unpack (RNE)
__device__ __forceinline__ unsigned short f2bf(float f) {
  unsigned u = __float_as_uint(f);
  return (unsigned short)((u + 0x7fffu + ((u >> 16) & 1u)) >> 16);
}
__device__ __forceinline__ float bf2f(unsigned short b) {
  return __uint_as_float(((unsigned)b) << 16);
}

// ---- pass 1: per-block bucket histogram + global per-node degree (atomics
//      write through exactly 4B); also zero gsum ----
__global__ __launch_bounds__(256) void k_cnt(const int* __restrict__ ei,
                                             int* __restrict__ cnt,
                                             float* __restrict__ gsum,
                                             int* __restrict__ deg) {
  __shared__ int h[NBUCK];
  int t = threadIdx.x;
  for (int i = t; i < NBUCK; i += 256) h[i] = 0;
  int gi = blockIdx.x * 256 + t;
  if (gi < N_GRAPHS * 64) gsum[gi] = 0.f;
  __syncthreads();
  int start = blockIdx.x * CHUNK, end = min(start + CHUNK, N_EDGES);
  for (int e = start + t; e < end; e += 256) {
    int dst = ei[N_EDGES + e];
    atomicAdd(&h[dst >> BSH], 1);
    atomicAdd(&deg[dst], 1);
  }
  __syncthreads();
  for (int b = t; b < NBUCK; b += 256)
    cnt[b * FBLK + blockIdx.x] = h[b];
}

// ---- dual role: blocks 0..NBUCK-1: per-bucket exclusive scan of the 512
//      block counts (writes tot); remaining blocks: encoder + BN + h@W_gcn,
//      pre-scaled by dis = rsqrt(deg+1) computed inline -> hws (bf16) ----
__global__ __launch_bounds__(256) void k_scan_enc(
    int* __restrict__ cnt, int* __restrict__ tot, const int* __restrict__ deg,
    const float* __restrict__ x,
    const float* __restrict__ Wenc, const float* __restrict__ benc,
    const float* __restrict__ gamma, const float* __restrict__ beta,
    const float* __restrict__ mean,  const float* __restrict__ var,
    const float* __restrict__ Wgcn,
    unsigned short* __restrict__ hws) {
  int t = threadIdx.x;
  int lane = t & 63, w = t >> 6;
  if (blockIdx.x < NBUCK) {
    __shared__ int wsum[4];
    int b = blockIdx.x;
    int v0 = cnt[b * FBLK + 2 * t], v1 = cnt[b * FBLK + 2 * t + 1];
    int a = v0 + v1;
    int incl = a;
    #pragma unroll
    for (int off = 1; off < 64; off <<= 1) {
      int y = __shfl_up(incl, off);
      if (lane >= off) incl += y;
    }
    if (lane == 63) wsum[w] = incl;
    __syncthreads();
    if (t == 0) {
      int s = 0;
      #pragma unroll
      for (int i = 0; i < 4; ++i) { int x2 = wsum[i]; wsum[i] = s; s += x2; }
      tot[b] = s;
    }
    __syncthreads();
    int excl = wsum[w] + incl - a;
    cnt[b * FBLK + 2 * t] = excl;
    cnt[b * FBLK + 2 * t + 1] = excl + v0;
    return;
  }
  // ------- encoder role -------
  int wv = (blockIdx.x - NBUCK) * 4 + w;           // 16 nodes per wave
  if (wv >= 6250) return;
  float be = benc[lane];
  float sc = gamma[lane] * rsqrtf(var[lane] + 1e-5f);
  float mu = mean[lane], bt = beta[lane];
  float w0 = Wenc[lane], w1 = Wenc[64 + lane], w2 = Wenc[128 + lane], w3 = Wenc[192 + lane];
  float wreg[64];
  #pragma unroll
  for (int k = 0; k < 64; ++k) wreg[k] = Wgcn[k * 64 + lane];   // W column j=lane
  int n0 = wv * 16;
  for (int i = 0; i < 16; ++i) {
    int n = n0 + i;                                  // 6250*16 = 100000 exact
    float4 xv = ((const float4*)x)[n];               // wave-uniform broadcast
    float h = fmaf(xv.w, w3, fmaf(xv.z, w2, fmaf(xv.y, w1, fmaf(xv.x, w0, be))));
    h = fmaxf(h, 0.f);                               // ReLU (dropout = identity)
    float hbn = (h - mu) * sc + bt;                  // BatchNorm (running stats)
    int hb = __float_as_int(hbn);
    float a0 = 0.f, a1 = 0.f, a2 = 0.f, a3 = 0.f;
    #pragma unroll
    for (int k = 0; k < 64; k += 4) {
      a0 = fmaf(__int_as_float(__builtin_amdgcn_readlane(hb, k)),     wreg[k],     a0);
      a1 = fmaf(__int_as_float(__builtin_amdgcn_readlane(hb, k + 1)), wreg[k + 1], a1);
      a2 = fmaf(__int_as_float(__builtin_amdgcn_readlane(hb, k + 2)), wreg[k + 2], a2);
      a3 = fmaf(__int_as_float(__builtin_amdgcn_readlane(hb, k + 3)), wreg[k + 3], a3);
    }
    float dis_n = rsqrtf((float)(deg[n] + 1));       // +1 self-loop
    float acc = ((a0 + a1) + (a2 + a3)) * dis_n;
    hws[(size_t)n * 64 + lane] = f2bf(acc);
  }
}

// ---- pass 2: deterministic fill; bucket-base scan in LDS (196 entries) ----
__global__ __launch_bounds__(256) void k_fill(const int* __restrict__ ei,
                                              const int* __restrict__ cnt,
                                              const int* __restrict__ tot,
                                              int* __restrict__ binned) {
  __shared__ int cur[NBUCK];
  __shared__ int wsum[4];
  int t = threadIdx.x, blk = blockIdx.x;
  int lane = t & 63, w = t >> 6;
  int v = (t < NBUCK) ? tot[t] : 0;
  int incl = v;
  #pragma unroll
  for (int off = 1; off < 64; off <<= 1) {
    int y = __shfl_up(incl, off);
    if (lane >= off) incl += y;
  }
  if (lane == 63) wsum[w] = incl;
  __syncthreads();
  if (t == 0) {
    int s = 0;
    #pragma unroll
    for (int i = 0; i < 4; ++i) { int x2 = wsum[i]; wsum[i] = s; s += x2; }
  }
  __syncthreads();
  if (t < NBUCK) cur[t] = (wsum[w] + incl - v) + cnt[t * FBLK + blk];
  __syncthreads();
  int start = blk * CHUNK, end = min(start + CHUNK, N_EDGES);
  for (int e = start + t; e < end; e += 256) {
    int src = ei[e];
    int dst = ei[N_EDGES + e];
    int b = dst >> BSH;
    int p = atomicAdd(&cur[b], 1);                 // LDS atomic
    binned[p] = src | ((dst & (BNODES - 1)) << 17);
  }
}

// ---- per-bucket (512 thr): base reduce + LDS hist+scan -> row_start, sort ----
__global__ __launch_bounds__(512) void k_csr(const int* __restrict__ tot,
                                             const int* __restrict__ binned,
                                             int* __restrict__ csr,
                                             int* __restrict__ row_start) {
  __shared__ int hist[BNODES];
  __shared__ int wsum[8];
  __shared__ int b0S;
  int t = threadIdx.x;
  int blk = blockIdx.x;
  int lane = t & 63, w = t >> 6;
  // b0 = sum of tot[0..blk-1]
  int pv = 0;
  for (int i = t; i < blk; i += 512) pv += tot[i];
  #pragma unroll
  for (int off = 32; off > 0; off >>= 1) pv += __shfl_down(pv, off);
  if (lane == 0) wsum[w] = pv;
  hist[t] = 0;
  __syncthreads();
  if (t == 0) {
    int s = 0;
    #pragma unroll
    for (int i = 0; i < 8; ++i) s += wsum[i];
    b0S = s;
  }
  __syncthreads();
  int b0 = b0S;
  int nE = tot[blk];
  int node0 = blk << BSH;
  for (int i = t; i < nE; i += 512)
    atomicAdd(&hist[(unsigned)binned[b0 + i] >> 17], 1);
  __syncthreads();
  int v = hist[t];                         // in-bucket degree of node t
  int incl = v;
  #pragma unroll
  for (int off = 1; off < 64; off <<= 1) {
    int y = __shfl_up(incl, off);
    if (lane >= off) incl += y;
  }
  if (lane == 63) wsum[w] = incl;
  __syncthreads();
  if (t == 0) {
    int s = 0;
    #pragma unroll
    for (int i = 0; i < 8; ++i) { int x2 = wsum[i]; wsum[i] = s; s += x2; }
  }
  __syncthreads();
  int excl = wsum[w] + incl - v;
  hist[t] = excl;                          // reuse hist as scatter cursor
  int node = node0 + t;
  if (node < N_NODES) row_start[node] = b0 + excl;
  if (t == 0 && blk == NBUCK - 1) row_start[N_NODES] = N_EDGES;
  __syncthreads();
  for (int i = t; i < nE; i += 512) {
    int vv = binned[b0 + i];
    int d = (unsigned)vv >> 17;
    int p = atomicAdd(&hist[d], 1);
    csr[b0 + p] = vv & 0x1FFFF;            // scatter confined to ~25KB region
  }
}

// ---- CSR gather: 64-thr blocks (uniform node idx -> scalar readlane +
//      SGPR-base loads), 8-deep MLP; dn derived from row bounds ----
__global__ __launch_bounds__(64) void k_gather(
    const int* __restrict__ row_start, const int* __restrict__ csr,
    const unsigned short* __restrict__ hws,
    const int* __restrict__ batch, const float* __restrict__ bgcn,
    float* __restrict__ gsum) {
  int lane = threadIdx.x;              // one wave per block
  int nb = blockIdx.x * 4;             // 25000 blocks, no tail
  float bias = bgcn[lane];
  float vout[4];
  int gid[4];
  #pragma unroll
  for (int k = 0; k < 4; ++k) {
    int n = nb + k;                    // uniform: blockIdx-derived only
    int st = row_start[n], en = row_start[n + 1];
    float dn = rsqrtf((float)(en - st + 1));   // deg + self-loop
    float a0 = 0.f, a1 = 0.f, a2 = 0.f, a3 = 0.f;
    for (int c = st; c < en; c += 64) {
      int m = min(64, en - c);         // uniform
      int chunk = (c + lane < en) ? csr[c + lane] : 0;   // coalesced load
      int j = 0;
      for (; j + 8 <= m; j += 8) {     // j uniform -> v_readlane w/ SGPR idx
        int s0 = __builtin_amdgcn_readlane(chunk, j);
        int s1 = __builtin_amdgcn_readlane(chunk, j + 1);
        int s2 = __builtin_amdgcn_readlane(chunk, j + 2);
        int s3 = __builtin_amdgcn_readlane(chunk, j + 3);
        int s4 = __builtin_amdgcn_readlane(chunk, j + 4);
        int s5 = __builtin_amdgcn_readlane(chunk, j + 5);
        int s6 = __builtin_amdgcn_readlane(chunk, j + 6);
        int s7 = __builtin_amdgcn_readlane(chunk, j + 7);
        float r0 = bf2f(hws[(size_t)s0 * 64 + lane]);
        float r1 = bf2f(hws[(size_t)s1 * 64 + lane]);
        float r2 = bf2f(hws[(size_t)s2 * 64 + lane]);
        float r3 = bf2f(hws[(size_t)s3 * 64 + lane]);
        float r4 = bf2f(hws[(size_t)s4 * 64 + lane]);
        float r5 = bf2f(hws[(size_t)s5 * 64 + lane]);
        float r6 = bf2f(hws[(size_t)s6 * 64 + lane]);
        float r7 = bf2f(hws[(size_t)s7 * 64 + lane]);
        a0 += r0; a1 += r1; a2 += r2; a3 += r3;
        a0 += r4; a1 += r5; a2 += r6; a3 += r7;
      }
      for (; j < m; ++j) {
        int s = __builtin_amdgcn_readlane(chunk, j);
        a0 += bf2f(hws[(size_t)s * 64 + lane]);
      }
    }
    float self = bf2f(hws[(size_t)n * 64 + lane]);
    vout[k] = fmaxf(dn * (((a0 + a1) + (a2 + a3)) + self) + bias, 0.f);
    gid[k] = batch[n];
  }
  float vs = vout[0];
  int cg = gid[0];
  #pragma unroll
  for (int k = 1; k < 4; ++k) {
    if (gid[k] == cg) vs += vout[k];
    else {
      atomicAdd(&gsum[cg * 64 + lane], vs);
      vs = vout[k]; cg = gid[k];
    }
  }
  atomicAdd(&gsum[cg * 64 + lane], vs);
}

// ---- classifier; graph count via binary search on sorted batch ----
__global__ void k_cls(const float* __restrict__ gsum, const int* __restrict__ batch,
                      const float* __restrict__ W1, const float* __restrict__ b1,
                      const float* __restrict__ W2, const float* __restrict__ b2,
                      float* __restrict__ out) {
  __shared__ float gm[64];
  __shared__ int cntS;
  int j = threadIdx.x;
  int g = blockIdx.x;
  if (j == 0) {
    int lo = 0, hi = N_NODES;
    while (lo < hi) { int mid = (lo + hi) >> 1; if (batch[mid] < g) lo = mid + 1; else hi = mid; }
    int lo2 = lo, hi2 = N_NODES;
    while (lo2 < hi2) { int mid = (lo2 + hi2) >> 1; if (batch[mid] < g + 1) lo2 = mid + 1; else hi2 = mid; }
    cntS = lo2 - lo;
  }
  __syncthreads();
  float denom = fmaxf((float)cntS, 1.0f);
  gm[j] = gsum[g * 64 + j] / denom;
  __syncthreads();
  float hid = b1[j];
  #pragma unroll
  for (int k = 0; k < 64; ++k) hid += gm[k] * W1[k * 64 + j];
  hid = fmaxf(hid, 0.f);
  float o0 = hid * W2[j * 2 + 0];
  float o1 = hid * W2[j * 2 + 1];
  #pragma unroll
  for (int off = 32; off > 0; off >>= 1) {
    o0 += __shfl_down(o0, off);
    o1 += __shfl_down(o1, off);
  }
  if (j == 0) {
    out[g * 2 + 0] = o0 + b2[0];
    out[g * 2 + 1] = o1 + b2[1];
  }
}

extern "C" void kernel_launch(void* const* d_in, const int* in_sizes, int n_in,
                              void* d_out, int out_size, void* d_ws, size_t ws_size,
                              hipStream_t stream) {
  const float* x     = (const float*)d_in[0];
  const int*   ei    = (const int*)d_in[1];
  const int*   batch = (const int*)d_in[2];
  const float* Wenc  = (const float*)d_in[3];
  const float* benc  = (const float*)d_in[4];
  const float* gamma = (const float*)d_in[5];
  const float* beta  = (const float*)d_in[6];
  const float* mean  = (const float*)d_in[7];
  const float* var   = (const float*)d_in[8];
  const float* Wgcn  = (const float*)d_in[9];
  const float* bgcn  = (const float*)d_in[10];
  const float* W1    = (const float*)d_in[11];
  const float* b1    = (const float*)d_in[12];
  const float* W2    = (const float*)d_in[13];
  const float* b2    = (const float*)d_in[14];
  float* out = (float*)d_out;

  char* ws = (char*)d_ws;
  float*          gsum      = (float*)ws;          ws += (size_t)N_GRAPHS * 64 * 4;
  int*            deg       = (int*)ws;            ws += (size_t)N_NODES * 4;
  int*            cnt       = (int*)ws;            ws += (size_t)NBUCK * FBLK * 4;
  int*            tot       = (int*)ws;            ws += 256 * 4;
  int*            binned    = (int*)ws;            ws += (size_t)N_EDGES * 4;
  int*            csr       = (int*)ws;            ws += (size_t)N_EDGES * 4;
  int*            row_start = (int*)ws;            ws += (size_t)(N_NODES + 32) * 4;
  unsigned short* hws       = (unsigned short*)ws; ws += (size_t)N_NODES * 64 * 2;

  hipMemsetAsync(deg, 0, (size_t)N_NODES * 4, stream);
  k_cnt<<<FBLK, 256, 0, stream>>>(ei, cnt, gsum, deg);
  k_scan_enc<<<NBUCK + ENC_BLOCKS, 256, 0, stream>>>(cnt, tot, deg, x, Wenc, benc,
                                                     gamma, beta, mean, var, Wgcn, hws);
  k_fill<<<FBLK, 256, 0, stream>>>(ei, cnt, tot, binned);
  k_csr<<<NBUCK, 512, 0, stream>>>(tot, binned, csr, row_start);
  k_gather<<<(N_NODES / 4), 64, 0, stream>>>(row_start, csr, hws, batch, bgcn, gsum);
  k_cls<<<N_GRAPHS, 64, 0, stream>>>(gsum, batch, W1, b1, W2, b2, out);
}

// Round 12
// 196.671 us; speedup vs baseline: 1.2176x; 1.2176x over previous
//
#include <hip/hip_runtime.h>

#define N_NODES  100000
#define N_EDGES  1200000
#define N_GRAPHS 1024

#define BSH    9                     // 512-node buckets
#define BNODES 512
#define NBUCK  196                   // ceil(100000/512)
#define FBLK   512                   // cnt/fill blocks
#define CHUNK  ((N_EDGES + FBLK - 1) / FBLK)   // 2344
#define ENC_BLOCKS 1563              // ceil(6250 enc-waves / 4)

// bf16 pack/unpack (RNE)
__device__ __forceinline__ unsigned short f2bf(float f) {
  unsigned u = __float_as_uint(f);
  return (unsigned short)((u + 0x7fffu + ((u >> 16) & 1u)) >> 16);
}
__device__ __forceinline__ float bf2f(unsigned short b) {
  return __uint_as_float(((unsigned)b) << 16);
}

// ---- pass 1: per-block bucket histogram -> cnt[b*FBLK+blk]; zero gsum ----
__global__ __launch_bounds__(256) void k_cnt(const int* __restrict__ ei,
                                             int* __restrict__ cnt,
                                             float* __restrict__ gsum) {
  __shared__ int h[NBUCK];
  int t = threadIdx.x;
  for (int i = t; i < NBUCK; i += 256) h[i] = 0;
  int gi = blockIdx.x * 256 + t;
  if (gi < N_GRAPHS * 64) gsum[gi] = 0.f;
  __syncthreads();
  int start = blockIdx.x * CHUNK, end = min(start + CHUNK, N_EDGES);
  for (int e = start + t; e < end; e += 256)
    atomicAdd(&h[ei[N_EDGES + e] >> BSH], 1);
  __syncthreads();
  for (int b = t; b < NBUCK; b += 256)
    cnt[b * FBLK + blockIdx.x] = h[b];
}

// ---- dual role: blocks 0..NBUCK-1: per-bucket exclusive scan of the 512
//      block counts (writes tot); remaining blocks: encoder + BN + h@W_gcn
//      -> hw (bf16, UNscaled — no dis dependency) ----
__global__ __launch_bounds__(256) void k_scan_enc(
    int* __restrict__ cnt, int* __restrict__ tot,
    const float* __restrict__ x,
    const float* __restrict__ Wenc, const float* __restrict__ benc,
    const float* __restrict__ gamma, const float* __restrict__ beta,
    const float* __restrict__ mean,  const float* __restrict__ var,
    const float* __restrict__ Wgcn,
    unsigned short* __restrict__ hw) {
  int t = threadIdx.x;
  int lane = t & 63, w = t >> 6;
  if (blockIdx.x < NBUCK) {
    __shared__ int wsum[4];
    int b = blockIdx.x;
    int v0 = cnt[b * FBLK + 2 * t], v1 = cnt[b * FBLK + 2 * t + 1];
    int a = v0 + v1;
    int incl = a;
    #pragma unroll
    for (int off = 1; off < 64; off <<= 1) {
      int y = __shfl_up(incl, off);
      if (lane >= off) incl += y;
    }
    if (lane == 63) wsum[w] = incl;
    __syncthreads();
    if (t == 0) {
      int s = 0;
      #pragma unroll
      for (int i = 0; i < 4; ++i) { int x2 = wsum[i]; wsum[i] = s; s += x2; }
      tot[b] = s;
    }
    __syncthreads();
    int excl = wsum[w] + incl - a;
    cnt[b * FBLK + 2 * t] = excl;
    cnt[b * FBLK + 2 * t + 1] = excl + v0;
    return;
  }
  // ------- encoder role -------
  int wv = (blockIdx.x - NBUCK) * 4 + w;           // 16 nodes per wave
  if (wv >= 6250) return;
  float be = benc[lane];
  float sc = gamma[lane] * rsqrtf(var[lane] + 1e-5f);
  float mu = mean[lane], bt = beta[lane];
  float w0 = Wenc[lane], w1 = Wenc[64 + lane], w2 = Wenc[128 + lane], w3 = Wenc[192 + lane];
  float wreg[64];
  #pragma unroll
  for (int k = 0; k < 64; ++k) wreg[k] = Wgcn[k * 64 + lane];   // W column j=lane
  int n0 = wv * 16;
  for (int i = 0; i < 16; ++i) {
    int n = n0 + i;                                  // 6250*16 = 100000 exact
    float4 xv = ((const float4*)x)[n];               // wave-uniform broadcast
    float h = fmaf(xv.w, w3, fmaf(xv.z, w2, fmaf(xv.y, w1, fmaf(xv.x, w0, be))));
    h = fmaxf(h, 0.f);                               // ReLU (dropout = identity)
    float hbn = (h - mu) * sc + bt;                  // BatchNorm (running stats)
    int hb = __float_as_int(hbn);
    float a0 = 0.f, a1 = 0.f, a2 = 0.f, a3 = 0.f;
    #pragma unroll
    for (int k = 0; k < 64; k += 4) {
      a0 = fmaf(__int_as_float(__builtin_amdgcn_readlane(hb, k)),     wreg[k],     a0);
      a1 = fmaf(__int_as_float(__builtin_amdgcn_readlane(hb, k + 1)), wreg[k + 1], a1);
      a2 = fmaf(__int_as_float(__builtin_amdgcn_readlane(hb, k + 2)), wreg[k + 2], a2);
      a3 = fmaf(__int_as_float(__builtin_amdgcn_readlane(hb, k + 3)), wreg[k + 3], a3);
    }
    hw[(size_t)n * 64 + lane] = f2bf((a0 + a1) + (a2 + a3));
  }
}

// ---- pass 2: deterministic fill; bucket-base scan in LDS (196 entries) ----
__global__ __launch_bounds__(256) void k_fill(const int* __restrict__ ei,
                                              const int* __restrict__ cnt,
                                              const int* __restrict__ tot,
                                              int* __restrict__ binned) {
  __shared__ int cur[NBUCK];
  __shared__ int wsum[4];
  int t = threadIdx.x, blk = blockIdx.x;
  int lane = t & 63, w = t >> 6;
  int v = (t < NBUCK) ? tot[t] : 0;
  int incl = v;
  #pragma unroll
  for (int off = 1; off < 64; off <<= 1) {
    int y = __shfl_up(incl, off);
    if (lane >= off) incl += y;
  }
  if (lane == 63) wsum[w] = incl;
  __syncthreads();
  if (t == 0) {
    int s = 0;
    #pragma unroll
    for (int i = 0; i < 4; ++i) { int x2 = wsum[i]; wsum[i] = s; s += x2; }
  }
  __syncthreads();
  if (t < NBUCK) cur[t] = (wsum[w] + incl - v) + cnt[t * FBLK + blk];
  __syncthreads();
  int start = blk * CHUNK, end = min(start + CHUNK, N_EDGES);
  for (int e = start + t; e < end; e += 256) {
    int src = ei[e];
    int dst = ei[N_EDGES + e];
    int b = dst >> BSH;
    int p = atomicAdd(&cur[b], 1);                 // LDS atomic
    binned[p] = src | ((dst & (BNODES - 1)) << 17);
  }
}

// ---- per-bucket (512 thr): base reduce + LDS hist+scan -> row_start/dis, sort ----
__global__ __launch_bounds__(512) void k_csr(const int* __restrict__ tot,
                                             const int* __restrict__ binned,
                                             int* __restrict__ csr,
                                             int* __restrict__ row_start,
                                             float* __restrict__ dis) {
  __shared__ int hist[BNODES];
  __shared__ int wsum[8];
  __shared__ int b0S;
  int t = threadIdx.x;
  int blk = blockIdx.x;
  int lane = t & 63, w = t >> 6;
  // b0 = sum of tot[0..blk-1]
  int pv = (t < blk) ? tot[t] : 0;                 // blk <= 195 < 512
  #pragma unroll
  for (int off = 32; off > 0; off >>= 1) pv += __shfl_down(pv, off);
  if (lane == 0) wsum[w] = pv;
  hist[t] = 0;
  __syncthreads();
  if (t == 0) {
    int s = 0;
    #pragma unroll
    for (int i = 0; i < 8; ++i) s += wsum[i];
    b0S = s;
  }
  __syncthreads();
  int b0 = b0S;
  int nE = tot[blk];
  int node0 = blk << BSH;
  for (int i = t; i < nE; i += 512)
    atomicAdd(&hist[(unsigned)binned[b0 + i] >> 17], 1);
  __syncthreads();
  int v = hist[t];                         // full in-degree of node t (buckets partition dst)
  int incl = v;
  #pragma unroll
  for (int off = 1; off < 64; off <<= 1) {
    int y = __shfl_up(incl, off);
    if (lane >= off) incl += y;
  }
  if (lane == 63) wsum[w] = incl;
  __syncthreads();
  if (t == 0) {
    int s = 0;
    #pragma unroll
    for (int i = 0; i < 8; ++i) { int x2 = wsum[i]; wsum[i] = s; s += x2; }
  }
  __syncthreads();
  int excl = wsum[w] + incl - v;
  hist[t] = excl;                          // reuse hist as scatter cursor
  int node = node0 + t;
  if (node < N_NODES) {
    row_start[node] = b0 + excl;
    dis[node] = rsqrtf((float)(v + 1));    // +1 self-loop
  }
  if (t == 0 && blk == NBUCK - 1) row_start[N_NODES] = N_EDGES;
  __syncthreads();
  for (int i = t; i < nE; i += 512) {
    int vv = binned[b0 + i];
    int d = (unsigned)vv >> 17;
    int p = atomicAdd(&hist[d], 1);
    csr[b0 + p] = vv & 0x1FFFF;            // scatter confined to ~25KB region
  }
}

// ---- CSR gather: 64-thr blocks, scalar readlane idx -> s_load dis + row load,
//      8-deep MLP; dn from row bounds ----
__global__ __launch_bounds__(64) void k_gather(
    const int* __restrict__ row_start, const int* __restrict__ csr,
    const float* __restrict__ dis, const unsigned short* __restrict__ hw,
    const int* __restrict__ batch, const float* __restrict__ bgcn,
    float* __restrict__ gsum) {
  int lane = threadIdx.x;              // one wave per block
  int nb = blockIdx.x * 4;             // 25000 blocks, no tail
  float bias = bgcn[lane];
  float vout[4];
  int gid[4];
  #pragma unroll
  for (int k = 0; k < 4; ++k) {
    int n = nb + k;                    // uniform: blockIdx-derived only
    int st = row_start[n], en = row_start[n + 1];
    float dn = rsqrtf((float)(en - st + 1));   // deg + self-loop
    float a0 = 0.f, a1 = 0.f, a2 = 0.f, a3 = 0.f;
    for (int c = st; c < en; c += 64) {
      int m = min(64, en - c);         // uniform
      int chunk = (c + lane < en) ? csr[c + lane] : 0;   // coalesced load
      int j = 0;
      for (; j + 8 <= m; j += 8) {     // j uniform -> scalar readlane + s_load dis
        int s0 = __builtin_amdgcn_readlane(chunk, j);
        int s1 = __builtin_amdgcn_readlane(chunk, j + 1);
        int s2 = __builtin_amdgcn_readlane(chunk, j + 2);
        int s3 = __builtin_amdgcn_readlane(chunk, j + 3);
        int s4 = __builtin_amdgcn_readlane(chunk, j + 4);
        int s5 = __builtin_amdgcn_readlane(chunk, j + 5);
        int s6 = __builtin_amdgcn_readlane(chunk, j + 6);
        int s7 = __builtin_amdgcn_readlane(chunk, j + 7);
        float d0 = dis[s0], d1 = dis[s1], d2 = dis[s2], d3 = dis[s3];
        float d4 = dis[s4], d5 = dis[s5], d6 = dis[s6], d7 = dis[s7];
        a0 = fmaf(d0, bf2f(hw[(size_t)s0 * 64 + lane]), a0);
        a1 = fmaf(d1, bf2f(hw[(size_t)s1 * 64 + lane]), a1);
        a2 = fmaf(d2, bf2f(hw[(size_t)s2 * 64 + lane]), a2);
        a3 = fmaf(d3, bf2f(hw[(size_t)s3 * 64 + lane]), a3);
        a0 = fmaf(d4, bf2f(hw[(size_t)s4 * 64 + lane]), a0);
        a1 = fmaf(d5, bf2f(hw[(size_t)s5 * 64 + lane]), a1);
        a2 = fmaf(d6, bf2f(hw[(size_t)s6 * 64 + lane]), a2);
        a3 = fmaf(d7, bf2f(hw[(size_t)s7 * 64 + lane]), a3);
      }
      for (; j < m; ++j) {
        int s = __builtin_amdgcn_readlane(chunk, j);
        a0 = fmaf(dis[s], bf2f(hw[(size_t)s * 64 + lane]), a0);
      }
    }
    float self = bf2f(hw[(size_t)n * 64 + lane]);
    float sum = (a0 + a1) + (a2 + a3);
    vout[k] = fmaxf(dn * fmaf(dn, self, sum) + bias, 0.f);
    gid[k] = batch[n];
  }
  float vs = vout[0];
  int cg = gid[0];
  #pragma unroll
  for (int k = 1; k < 4; ++k) {
    if (gid[k] == cg) vs += vout[k];
    else {
      atomicAdd(&gsum[cg * 64 + lane], vs);
      vs = vout[k]; cg = gid[k];
    }
  }
  atomicAdd(&gsum[cg * 64 + lane], vs);
}

// ---- classifier; graph count via binary search on sorted batch ----
__global__ void k_cls(const float* __restrict__ gsum, const int* __restrict__ batch,
                      const float* __restrict__ W1, const float* __restrict__ b1,
                      const float* __restrict__ W2, const float* __restrict__ b2,
                      float* __restrict__ out) {
  __shared__ float gm[64];
  __shared__ int cntS;
  int j = threadIdx.x;
  int g = blockIdx.x;
  if (j == 0) {
    int lo = 0, hi = N_NODES;
    while (lo < hi) { int mid = (lo + hi) >> 1; if (batch[mid] < g) lo = mid + 1; else hi = mid; }
    int lo2 = lo, hi2 = N_NODES;
    while (lo2 < hi2) { int mid = (lo2 + hi2) >> 1; if (batch[mid] < g + 1) lo2 = mid + 1; else hi2 = mid; }
    cntS = lo2 - lo;
  }
  __syncthreads();
  float denom = fmaxf((float)cntS, 1.0f);
  gm[j] = gsum[g * 64 + j] / denom;
  __syncthreads();
  float hid = b1[j];
  #pragma unroll
  for (int k = 0; k < 64; ++k) hid += gm[k] * W1[k * 64 + j];
  hid = fmaxf(hid, 0.f);
  float o0 = hid * W2[j * 2 + 0];
  float o1 = hid * W2[j * 2 + 1];
  #pragma unroll
  for (int off = 32; off > 0; off >>= 1) {
    o0 += __shfl_down(o0, off);
    o1 += __shfl_down(o1, off);
  }
  if (j == 0) {
    out[g * 2 + 0] = o0 + b2[0];
    out[g * 2 + 1] = o1 + b2[1];
  }
}

extern "C" void kernel_launch(void* const* d_in, const int* in_sizes, int n_in,
                              void* d_out, int out_size, void* d_ws, size_t ws_size,
                              hipStream_t stream) {
  const float* x     = (const float*)d_in[0];
  const int*   ei    = (const int*)d_in[1];
  const int*   batch = (const int*)d_in[2];
  const float* Wenc  = (const float*)d_in[3];
  const float* benc  = (const float*)d_in[4];
  const float* gamma = (const float*)d_in[5];
  const float* beta  = (const float*)d_in[6];
  const float* mean  = (const float*)d_in[7];
  const float* var   = (const float*)d_in[8];
  const float* Wgcn  = (const float*)d_in[9];
  const float* bgcn  = (const float*)d_in[10];
  const float* W1    = (const float*)d_in[11];
  const float* b1    = (const float*)d_in[12];
  const float* W2    = (const float*)d_in[13];
  const float* b2    = (const float*)d_in[14];
  float* out = (float*)d_out;

  char* ws = (char*)d_ws;
  float*          gsum      = (float*)ws;          ws += (size_t)N_GRAPHS * 64 * 4;
  int*            cnt       = (int*)ws;            ws += (size_t)NBUCK * FBLK * 4;
  int*            tot       = (int*)ws;            ws += 256 * 4;
  int*            binned    = (int*)ws;            ws += (size_t)N_EDGES * 4;
  int*            csr       = (int*)ws;            ws += (size_t)N_EDGES * 4;
  int*            row_start = (int*)ws;            ws += (size_t)(N_NODES + 32) * 4;
  float*          dis       = (float*)ws;          ws += (size_t)N_NODES * 4;
  unsigned short* hw        = (unsigned short*)ws; ws += (size_t)N_NODES * 64 * 2;

  k_cnt<<<FBLK, 256, 0, stream>>>(ei, cnt, gsum);
  k_scan_enc<<<NBUCK + ENC_BLOCKS, 256, 0, stream>>>(cnt, tot, x, Wenc, benc,
                                                     gamma, beta, mean, var, Wgcn, hw);
  k_fill<<<FBLK, 256, 0, stream>>>(ei, cnt, tot, binned);
  k_csr<<<NBUCK, 512, 0, stream>>>(tot, binned, csr, row_start, dis);
  k_gather<<<(N_NODES / 4), 64, 0, stream>>>(row_start, csr, dis, hw, batch, bgcn, gsum);
  k_cls<<<N_GRAPHS, 64, 0, stream>>>(gsum, batch, W1, b1, W2, b2, out);
}

// Round 13
// 192.209 us; speedup vs baseline: 1.2458x; 1.0232x over previous
//
#include <hip/hip_runtime.h>

#define N_NODES  100000
#define N_EDGES  1200000
#define N_GRAPHS 1024

#define BSH    9                     // 512-node buckets
#define BNODES 512
#define NBUCK  196                   // ceil(100000/512)
#define FBLK   512                   // cnt/fill blocks
#define CHUNK  ((N_EDGES + FBLK - 1) / FBLK)   // 2344
#define ENC_BLOCKS 1563              // ceil(6250 enc-waves / 4)

// bf16 pack/unpack (RNE)
__device__ __forceinline__ unsigned short f2bf(float f) {
  unsigned u = __float_as_uint(f);
  return (unsigned short)((u + 0x7fffu + ((u >> 16) & 1u)) >> 16);
}
__device__ __forceinline__ float bf2f(unsigned short b) {
  return __uint_as_float(((unsigned)b) << 16);
}

// ---- pass 1: per-block bucket histogram -> cnt[b*FBLK+blk]; zero gsum ----
__global__ __launch_bounds__(256) void k_cnt(const int* __restrict__ ei,
                                             int* __restrict__ cnt,
                                             float* __restrict__ gsum) {
  __shared__ int h[NBUCK];
  int t = threadIdx.x;
  for (int i = t; i < NBUCK; i += 256) h[i] = 0;
  int gi = blockIdx.x * 256 + t;
  if (gi < N_GRAPHS * 64) gsum[gi] = 0.f;
  __syncthreads();
  int start = blockIdx.x * CHUNK, end = min(start + CHUNK, N_EDGES);
  for (int e = start + t; e < end; e += 256)
    atomicAdd(&h[ei[N_EDGES + e] >> BSH], 1);
  __syncthreads();
  for (int b = t; b < NBUCK; b += 256)
    cnt[b * FBLK + blockIdx.x] = h[b];
}

// ---- dual role: blocks 0..NBUCK-1: per-bucket exclusive scan of the 512
//      block counts; remaining blocks: encoder + BN + h@W_gcn -> hwf (fp32,
//      UNscaled — no dependency on graph structure, hides under the scan) ----
__global__ __launch_bounds__(256) void k_scan_enc(
    int* __restrict__ cnt, int* __restrict__ tot,
    const float* __restrict__ x,
    const float* __restrict__ Wenc, const float* __restrict__ benc,
    const float* __restrict__ gamma, const float* __restrict__ beta,
    const float* __restrict__ mean,  const float* __restrict__ var,
    const float* __restrict__ Wgcn,
    float* __restrict__ hwf) {
  int t = threadIdx.x;
  int lane = t & 63, w = t >> 6;
  if (blockIdx.x < NBUCK) {
    __shared__ int wsum[4];
    int b = blockIdx.x;
    int v0 = cnt[b * FBLK + 2 * t], v1 = cnt[b * FBLK + 2 * t + 1];
    int a = v0 + v1;
    int incl = a;
    #pragma unroll
    for (int off = 1; off < 64; off <<= 1) {
      int y = __shfl_up(incl, off);
      if (lane >= off) incl += y;
    }
    if (lane == 63) wsum[w] = incl;
    __syncthreads();
    if (t == 0) {
      int s = 0;
      #pragma unroll
      for (int i = 0; i < 4; ++i) { int x2 = wsum[i]; wsum[i] = s; s += x2; }
      tot[b] = s;
    }
    __syncthreads();
    int excl = wsum[w] + incl - a;
    cnt[b * FBLK + 2 * t] = excl;
    cnt[b * FBLK + 2 * t + 1] = excl + v0;
    return;
  }
  // ------- encoder role -------
  int wv = (blockIdx.x - NBUCK) * 4 + w;           // 16 nodes per wave
  if (wv >= 6250) return;
  float be = benc[lane];
  float sc = gamma[lane] * rsqrtf(var[lane] + 1e-5f);
  float mu = mean[lane], bt = beta[lane];
  float w0 = Wenc[lane], w1 = Wenc[64 + lane], w2 = Wenc[128 + lane], w3 = Wenc[192 + lane];
  float wreg[64];
  #pragma unroll
  for (int k = 0; k < 64; ++k) wreg[k] = Wgcn[k * 64 + lane];   // W column j=lane
  int n0 = wv * 16;
  for (int i = 0; i < 16; ++i) {
    int n = n0 + i;                                  // 6250*16 = 100000 exact
    float4 xv = ((const float4*)x)[n];               // wave-uniform broadcast
    float h = fmaf(xv.w, w3, fmaf(xv.z, w2, fmaf(xv.y, w1, fmaf(xv.x, w0, be))));
    h = fmaxf(h, 0.f);                               // ReLU (dropout = identity)
    float hbn = (h - mu) * sc + bt;                  // BatchNorm (running stats)
    int hb = __float_as_int(hbn);
    float a0 = 0.f, a1 = 0.f, a2 = 0.f, a3 = 0.f;
    #pragma unroll
    for (int k = 0; k < 64; k += 4) {
      a0 = fmaf(__int_as_float(__builtin_amdgcn_readlane(hb, k)),     wreg[k],     a0);
      a1 = fmaf(__int_as_float(__builtin_amdgcn_readlane(hb, k + 1)), wreg[k + 1], a1);
      a2 = fmaf(__int_as_float(__builtin_amdgcn_readlane(hb, k + 2)), wreg[k + 2], a2);
      a3 = fmaf(__int_as_float(__builtin_amdgcn_readlane(hb, k + 3)), wreg[k + 3], a3);
    }
    hwf[(size_t)n * 64 + lane] = (a0 + a1) + (a2 + a3);
  }
}

// ---- pass 2: deterministic fill; bucket-base scan in LDS (196 entries) ----
__global__ __launch_bounds__(256) void k_fill(const int* __restrict__ ei,
                                              const int* __restrict__ cnt,
                                              const int* __restrict__ tot,
                                              int* __restrict__ binned) {
  __shared__ int cur[NBUCK];
  __shared__ int wsum[4];
  int t = threadIdx.x, blk = blockIdx.x;
  int lane = t & 63, w = t >> 6;
  int v = (t < NBUCK) ? tot[t] : 0;
  int incl = v;
  #pragma unroll
  for (int off = 1; off < 64; off <<= 1) {
    int y = __shfl_up(incl, off);
    if (lane >= off) incl += y;
  }
  if (lane == 63) wsum[w] = incl;
  __syncthreads();
  if (t == 0) {
    int s = 0;
    #pragma unroll
    for (int i = 0; i < 4; ++i) { int x2 = wsum[i]; wsum[i] = s; s += x2; }
  }
  __syncthreads();
  if (t < NBUCK) cur[t] = (wsum[w] + incl - v) + cnt[t * FBLK + blk];
  __syncthreads();
  int start = blk * CHUNK, end = min(start + CHUNK, N_EDGES);
  for (int e = start + t; e < end; e += 256) {
    int src = ei[e];
    int dst = ei[N_EDGES + e];
    int b = dst >> BSH;
    int p = atomicAdd(&cur[b], 1);                 // LDS atomic
    binned[p] = src | ((dst & (BNODES - 1)) << 17);
  }
}

// ---- per-bucket (512 thr): base reduce + LDS hist+scan -> row_start, sort csr;
//      epilogue scales this bucket's rows: hws = bf16(hwf * dis) ----
__global__ __launch_bounds__(512) void k_csr(const int* __restrict__ tot,
                                             const int* __restrict__ binned,
                                             int* __restrict__ csr,
                                             int* __restrict__ row_start,
                                             const float* __restrict__ hwf,
                                             unsigned short* __restrict__ hws) {
  __shared__ int hist[BNODES];
  __shared__ float disS[BNODES];
  __shared__ int wsum[8];
  __shared__ int b0S;
  int t = threadIdx.x;
  int blk = blockIdx.x;
  int lane = t & 63, w = t >> 6;
  // b0 = sum of tot[0..blk-1]
  int pv = (t < blk) ? tot[t] : 0;                 // blk <= 195 < 512
  #pragma unroll
  for (int off = 32; off > 0; off >>= 1) pv += __shfl_down(pv, off);
  if (lane == 0) wsum[w] = pv;
  hist[t] = 0;
  __syncthreads();
  if (t == 0) {
    int s = 0;
    #pragma unroll
    for (int i = 0; i < 8; ++i) s += wsum[i];
    b0S = s;
  }
  __syncthreads();
  int b0 = b0S;
  int nE = tot[blk];
  int node0 = blk << BSH;
  for (int i = t; i < nE; i += 512)
    atomicAdd(&hist[(unsigned)binned[b0 + i] >> 17], 1);
  __syncthreads();
  int v = hist[t];                         // full in-degree of node t (buckets partition dst)
  int incl = v;
  #pragma unroll
  for (int off = 1; off < 64; off <<= 1) {
    int y = __shfl_up(incl, off);
    if (lane >= off) incl += y;
  }
  if (lane == 63) wsum[w] = incl;
  __syncthreads();
  if (t == 0) {
    int s = 0;
    #pragma unroll
    for (int i = 0; i < 8; ++i) { int x2 = wsum[i]; wsum[i] = s; s += x2; }
  }
  __syncthreads();
  int excl = wsum[w] + incl - v;
  hist[t] = excl;                          // reuse hist as scatter cursor
  disS[t] = rsqrtf((float)(v + 1));        // +1 self-loop
  int node = node0 + t;
  if (node < N_NODES) row_start[node] = b0 + excl;
  if (t == 0 && blk == NBUCK - 1) row_start[N_NODES] = N_EDGES;
  __syncthreads();
  for (int i = t; i < nE; i += 512) {
    int vv = binned[b0 + i];
    int d = (unsigned)vv >> 17;
    int p = atomicAdd(&hist[d], 1);
    csr[b0 + p] = vv & 0x1FFFF;            // scatter confined to ~25KB region
  }
  // ---- epilogue: scale this bucket's rows (wave w owns nodes w*64..w*64+63) ----
  for (int i = 0; i < 64; ++i) {
    int n = node0 + w * 64 + i;
    if (n >= N_NODES) break;
    float d = disS[w * 64 + i];            // LDS broadcast, wave-uniform
    float val = hwf[(size_t)n * 64 + lane] * d;
    hws[(size_t)n * 64 + lane] = f2bf(val);
  }
}

// ---- CSR gather: 64-thr blocks, scalar readlane idx + SGPR-base row loads,
//      8/4/1 tiers; dn from row bounds; rows prescaled by dis ----
__global__ __launch_bounds__(64) void k_gather(
    const int* __restrict__ row_start, const int* __restrict__ csr,
    const unsigned short* __restrict__ hws,
    const int* __restrict__ batch, const float* __restrict__ bgcn,
    float* __restrict__ gsum) {
  int lane = threadIdx.x;              // one wave per block
  int nb = blockIdx.x * 4;             // 25000 blocks, no tail
  float bias = bgcn[lane];
  float vout[4];
  int gid[4];
  #pragma unroll
  for (int k = 0; k < 4; ++k) {
    int n = nb + k;                    // uniform: blockIdx-derived only
    int st = row_start[n], en = row_start[n + 1];
    float dn = rsqrtf((float)(en - st + 1));   // deg + self-loop
    float a0 = 0.f, a1 = 0.f, a2 = 0.f, a3 = 0.f;
    for (int c = st; c < en; c += 64) {
      int m = min(64, en - c);         // uniform
      int chunk = (c + lane < en) ? csr[c + lane] : 0;   // coalesced load
      int j = 0;
      for (; j + 8 <= m; j += 8) {     // j uniform -> v_readlane w/ SGPR idx
        int s0 = __builtin_amdgcn_readlane(chunk, j);
        int s1 = __builtin_amdgcn_readlane(chunk, j + 1);
        int s2 = __builtin_amdgcn_readlane(chunk, j + 2);
        int s3 = __builtin_amdgcn_readlane(chunk, j + 3);
        int s4 = __builtin_amdgcn_readlane(chunk, j + 4);
        int s5 = __builtin_amdgcn_readlane(chunk, j + 5);
        int s6 = __builtin_amdgcn_readlane(chunk, j + 6);
        int s7 = __builtin_amdgcn_readlane(chunk, j + 7);
        float r0 = bf2f(hws[(size_t)s0 * 64 + lane]);
        float r1 = bf2f(hws[(size_t)s1 * 64 + lane]);
        float r2 = bf2f(hws[(size_t)s2 * 64 + lane]);
        float r3 = bf2f(hws[(size_t)s3 * 64 + lane]);
        float r4 = bf2f(hws[(size_t)s4 * 64 + lane]);
        float r5 = bf2f(hws[(size_t)s5 * 64 + lane]);
        float r6 = bf2f(hws[(size_t)s6 * 64 + lane]);
        float r7 = bf2f(hws[(size_t)s7 * 64 + lane]);
        a0 += r0; a1 += r1; a2 += r2; a3 += r3;
        a0 += r4; a1 += r5; a2 += r6; a3 += r7;
      }
      for (; j + 4 <= m; j += 4) {
        int s0 = __builtin_amdgcn_readlane(chunk, j);
        int s1 = __builtin_amdgcn_readlane(chunk, j + 1);
        int s2 = __builtin_amdgcn_readlane(chunk, j + 2);
        int s3 = __builtin_amdgcn_readlane(chunk, j + 3);
        a0 += bf2f(hws[(size_t)s0 * 64 + lane]);
        a1 += bf2f(hws[(size_t)s1 * 64 + lane]);
        a2 += bf2f(hws[(size_t)s2 * 64 + lane]);
        a3 += bf2f(hws[(size_t)s3 * 64 + lane]);
      }
      for (; j < m; ++j) {
        int s = __builtin_amdgcn_readlane(chunk, j);
        a0 += bf2f(hws[(size_t)s * 64 + lane]);
      }
    }
    float self = bf2f(hws[(size_t)n * 64 + lane]);     // already dis-scaled
    vout[k] = fmaxf(dn * (((a0 + a1) + (a2 + a3)) + self) + bias, 0.f);
    gid[k] = batch[n];
  }
  float vs = vout[0];
  int cg = gid[0];
  #pragma unroll
  for (int k = 1; k < 4; ++k) {
    if (gid[k] == cg) vs += vout[k];
    else {
      atomicAdd(&gsum[cg * 64 + lane], vs);
      vs = vout[k]; cg = gid[k];
    }
  }
  atomicAdd(&gsum[cg * 64 + lane], vs);
}

// ---- classifier; graph count via binary search on sorted batch ----
__global__ void k_cls(const float* __restrict__ gsum, const int* __restrict__ batch,
                      const float* __restrict__ W1, const float* __restrict__ b1,
                      const float* __restrict__ W2, const float* __restrict__ b2,
                      float* __restrict__ out) {
  __shared__ float gm[64];
  __shared__ int cntS;
  int j = threadIdx.x;
  int g = blockIdx.x;
  if (j == 0) {
    int lo = 0, hi = N_NODES;
    while (lo < hi) { int mid = (lo + hi) >> 1; if (batch[mid] < g) lo = mid + 1; else hi = mid; }
    int lo2 = lo, hi2 = N_NODES;
    while (lo2 < hi2) { int mid = (lo2 + hi2) >> 1; if (batch[mid] < g + 1) lo2 = mid + 1; else hi2 = mid; }
    cntS = lo2 - lo;
  }
  __syncthreads();
  float denom = fmaxf((float)cntS, 1.0f);
  gm[j] = gsum[g * 64 + j] / denom;
  __syncthreads();
  float hid = b1[j];
  #pragma unroll
  for (int k = 0; k < 64; ++k) hid += gm[k] * W1[k * 64 + j];
  hid = fmaxf(hid, 0.f);
  float o0 = hid * W2[j * 2 + 0];
  float o1 = hid * W2[j * 2 + 1];
  #pragma unroll
  for (int off = 32; off > 0; off >>= 1) {
    o0 += __shfl_down(o0, off);
    o1 += __shfl_down(o1, off);
  }
  if (j == 0) {
    out[g * 2 + 0] = o0 + b2[0];
    out[g * 2 + 1] = o1 + b2[1];
  }
}

extern "C" void kernel_launch(void* const* d_in, const int* in_sizes, int n_in,
                              void* d_out, int out_size, void* d_ws, size_t ws_size,
                              hipStream_t stream) {
  const float* x     = (const float*)d_in[0];
  const int*   ei    = (const int*)d_in[1];
  const int*   batch = (const int*)d_in[2];
  const float* Wenc  = (const float*)d_in[3];
  const float* benc  = (const float*)d_in[4];
  const float* gamma = (const float*)d_in[5];
  const float* beta  = (const float*)d_in[6];
  const float* mean  = (const float*)d_in[7];
  const float* var   = (const float*)d_in[8];
  const float* Wgcn  = (const float*)d_in[9];
  const float* bgcn  = (const float*)d_in[10];
  const float* W1    = (const float*)d_in[11];
  const float* b1    = (const float*)d_in[12];
  const float* W2    = (const float*)d_in[13];
  const float* b2    = (const float*)d_in[14];
  float* out = (float*)d_out;

  char* ws = (char*)d_ws;
  float*          gsum      = (float*)ws;          ws += (size_t)N_GRAPHS * 64 * 4;
  int*            cnt       = (int*)ws;            ws += (size_t)NBUCK * FBLK * 4;
  int*            tot       = (int*)ws;            ws += 256 * 4;
  int*            binned    = (int*)ws;            ws += (size_t)N_EDGES * 4;
  int*            csr       = (int*)ws;            ws += (size_t)N_EDGES * 4;
  int*            row_start = (int*)ws;            ws += (size_t)(N_NODES + 32) * 4;
  float*          hwf       = (float*)ws;          ws += (size_t)N_NODES * 64 * 4;
  unsigned short* hws       = (unsigned short*)ws; ws += (size_t)N_NODES * 64 * 2;

  k_cnt<<<FBLK, 256, 0, stream>>>(ei, cnt, gsum);
  k_scan_enc<<<NBUCK + ENC_BLOCKS, 256, 0, stream>>>(cnt, tot, x, Wenc, benc,
                                                     gamma, beta, mean, var, Wgcn, hwf);
  k_fill<<<FBLK, 256, 0, stream>>>(ei, cnt, tot, binned);
  k_csr<<<NBUCK, 512, 0, stream>>>(tot, binned, csr, row_start, hwf, hws);
  k_gather<<<(N_NODES / 4), 64, 0, stream>>>(row_start, csr, hws, batch, bgcn, gsum);
  k_cls<<<N_GRAPHS, 64, 0, stream>>>(gsum, batch, W1, b1, W2, b2, out);
}

// Round 14
// 190.595 us; speedup vs baseline: 1.2564x; 1.0085x over previous
//
#include <hip/hip_runtime.h>

#define N_NODES  100000
#define N_EDGES  1200000
#define N_GRAPHS 1024

#define BSH    9                     // 512-node buckets
#define BNODES 512
#define NBUCK  196                   // ceil(100000/512)
#define FBLK   512                   // cnt/fill blocks
#define CHUNK  ((N_EDGES + FBLK - 1) / FBLK)   // 2344
#define ENC_BLOCKS 1563              // ceil(6250 enc-waves / 4)

// bf16 pack/unpack (RNE)
__device__ __forceinline__ unsigned short f2bf(float f) {
  unsigned u = __float_as_uint(f);
  return (unsigned short)((u + 0x7fffu + ((u >> 16) & 1u)) >> 16);
}
__device__ __forceinline__ float bf2f(unsigned short b) {
  return __uint_as_float(((unsigned)b) << 16);
}

// ---- pass 1: per-block bucket histogram -> cnt[b*FBLK+blk]; zero gsum ----
__global__ __launch_bounds__(256) void k_cnt(const int* __restrict__ ei,
                                             int* __restrict__ cnt,
                                             float* __restrict__ gsum) {
  __shared__ int h[NBUCK];
  int t = threadIdx.x;
  for (int i = t; i < NBUCK; i += 256) h[i] = 0;
  int gi = blockIdx.x * 256 + t;
  if (gi < N_GRAPHS * 64) gsum[gi] = 0.f;
  __syncthreads();
  int start = blockIdx.x * CHUNK, end = min(start + CHUNK, N_EDGES);
  for (int e = start + t; e < end; e += 256)
    atomicAdd(&h[ei[N_EDGES + e] >> BSH], 1);
  __syncthreads();
  for (int b = t; b < NBUCK; b += 256)
    cnt[b * FBLK + blockIdx.x] = h[b];
}

// ---- dual role: blocks 0..NBUCK-1: per-bucket exclusive scan of the 512
//      block counts; remaining blocks: encoder + BN + h@W_gcn -> hw
//      (bf16, UNscaled — dis applied per-edge in the gather) ----
__global__ __launch_bounds__(256) void k_scan_enc(
    int* __restrict__ cnt, int* __restrict__ tot,
    const float* __restrict__ x,
    const float* __restrict__ Wenc, const float* __restrict__ benc,
    const float* __restrict__ gamma, const float* __restrict__ beta,
    const float* __restrict__ mean,  const float* __restrict__ var,
    const float* __restrict__ Wgcn,
    unsigned short* __restrict__ hw) {
  int t = threadIdx.x;
  int lane = t & 63, w = t >> 6;
  if (blockIdx.x < NBUCK) {
    __shared__ int wsum[4];
    int b = blockIdx.x;
    int v0 = cnt[b * FBLK + 2 * t], v1 = cnt[b * FBLK + 2 * t + 1];
    int a = v0 + v1;
    int incl = a;
    #pragma unroll
    for (int off = 1; off < 64; off <<= 1) {
      int y = __shfl_up(incl, off);
      if (lane >= off) incl += y;
    }
    if (lane == 63) wsum[w] = incl;
    __syncthreads();
    if (t == 0) {
      int s = 0;
      #pragma unroll
      for (int i = 0; i < 4; ++i) { int x2 = wsum[i]; wsum[i] = s; s += x2; }
      tot[b] = s;
    }
    __syncthreads();
    int excl = wsum[w] + incl - a;
    cnt[b * FBLK + 2 * t] = excl;
    cnt[b * FBLK + 2 * t + 1] = excl + v0;
    return;
  }
  // ------- encoder role -------
  int wv = (blockIdx.x - NBUCK) * 4 + w;           // 16 nodes per wave
  if (wv >= 6250) return;
  float be = benc[lane];
  float sc = gamma[lane] * rsqrtf(var[lane] + 1e-5f);
  float mu = mean[lane], bt = beta[lane];
  float w0 = Wenc[lane], w1 = Wenc[64 + lane], w2 = Wenc[128 + lane], w3 = Wenc[192 + lane];
  float wreg[64];
  #pragma unroll
  for (int k = 0; k < 64; ++k) wreg[k] = Wgcn[k * 64 + lane];   // W column j=lane
  int n0 = wv * 16;
  for (int i = 0; i < 16; ++i) {
    int n = n0 + i;                                  // 6250*16 = 100000 exact
    float4 xv = ((const float4*)x)[n];               // wave-uniform broadcast
    float h = fmaf(xv.w, w3, fmaf(xv.z, w2, fmaf(xv.y, w1, fmaf(xv.x, w0, be))));
    h = fmaxf(h, 0.f);                               // ReLU (dropout = identity)
    float hbn = (h - mu) * sc + bt;                  // BatchNorm (running stats)
    int hb = __float_as_int(hbn);
    float a0 = 0.f, a1 = 0.f, a2 = 0.f, a3 = 0.f;
    #pragma unroll
    for (int k = 0; k < 64; k += 4) {
      a0 = fmaf(__int_as_float(__builtin_amdgcn_readlane(hb, k)),     wreg[k],     a0);
      a1 = fmaf(__int_as_float(__builtin_amdgcn_readlane(hb, k + 1)), wreg[k + 1], a1);
      a2 = fmaf(__int_as_float(__builtin_amdgcn_readlane(hb, k + 2)), wreg[k + 2], a2);
      a3 = fmaf(__int_as_float(__builtin_amdgcn_readlane(hb, k + 3)), wreg[k + 3], a3);
    }
    hw[(size_t)n * 64 + lane] = f2bf((a0 + a1) + (a2 + a3));
  }
}

// ---- pass 2: deterministic fill; bucket-base scan in LDS (196 entries) ----
__global__ __launch_bounds__(256) void k_fill(const int* __restrict__ ei,
                                              const int* __restrict__ cnt,
                                              const int* __restrict__ tot,
                                              int* __restrict__ binned) {
  __shared__ int cur[NBUCK];
  __shared__ int wsum[4];
  int t = threadIdx.x, blk = blockIdx.x;
  int lane = t & 63, w = t >> 6;
  int v = (t < NBUCK) ? tot[t] : 0;
  int incl = v;
  #pragma unroll
  for (int off = 1; off < 64; off <<= 1) {
    int y = __shfl_up(incl, off);
    if (lane >= off) incl += y;
  }
  if (lane == 63) wsum[w] = incl;
  __syncthreads();
  if (t == 0) {
    int s = 0;
    #pragma unroll
    for (int i = 0; i < 4; ++i) { int x2 = wsum[i]; wsum[i] = s; s += x2; }
  }
  __syncthreads();
  if (t < NBUCK) cur[t] = (wsum[w] + incl - v) + cnt[t * FBLK + blk];
  __syncthreads();
  int start = blk * CHUNK, end = min(start + CHUNK, N_EDGES);
  for (int e = start + t; e < end; e += 256) {
    int src = ei[e];
    int dst = ei[N_EDGES + e];
    int b = dst >> BSH;
    int p = atomicAdd(&cur[b], 1);                 // LDS atomic
    binned[p] = src | ((dst & (BNODES - 1)) << 17);
  }
}

// ---- per-bucket (512 thr): base reduce + LDS hist+scan -> row_start/dis, sort ----
__global__ __launch_bounds__(512) void k_csr(const int* __restrict__ tot,
                                             const int* __restrict__ binned,
                                             int* __restrict__ csr,
                                             int* __restrict__ row_start,
                                             float* __restrict__ dis) {
  __shared__ int hist[BNODES];
  __shared__ int wsum[8];
  __shared__ int b0S;
  int t = threadIdx.x;
  int blk = blockIdx.x;
  int lane = t & 63, w = t >> 6;
  // b0 = sum of tot[0..blk-1]
  int pv = (t < blk) ? tot[t] : 0;                 // blk <= 195 < 512
  #pragma unroll
  for (int off = 32; off > 0; off >>= 1) pv += __shfl_down(pv, off);
  if (lane == 0) wsum[w] = pv;
  hist[t] = 0;
  __syncthreads();
  if (t == 0) {
    int s = 0;
    #pragma unroll
    for (int i = 0; i < 8; ++i) s += wsum[i];
    b0S = s;
  }
  __syncthreads();
  int b0 = b0S;
  int nE = tot[blk];
  int node0 = blk << BSH;
  for (int i = t; i < nE; i += 512)
    atomicAdd(&hist[(unsigned)binned[b0 + i] >> 17], 1);
  __syncthreads();
  int v = hist[t];                         // full in-degree (buckets partition dst)
  int incl = v;
  #pragma unroll
  for (int off = 1; off < 64; off <<= 1) {
    int y = __shfl_up(incl, off);
    if (lane >= off) incl += y;
  }
  if (lane == 63) wsum[w] = incl;
  __syncthreads();
  if (t == 0) {
    int s = 0;
    #pragma unroll
    for (int i = 0; i < 8; ++i) { int x2 = wsum[i]; wsum[i] = s; s += x2; }
  }
  __syncthreads();
  int excl = wsum[w] + incl - v;
  hist[t] = excl;                          // reuse hist as scatter cursor
  int node = node0 + t;
  if (node < N_NODES) {
    row_start[node] = b0 + excl;
    dis[node] = rsqrtf((float)(v + 1));    // +1 self-loop
  }
  if (t == 0 && blk == NBUCK - 1) row_start[N_NODES] = N_EDGES;
  __syncthreads();
  for (int i = t; i < nE; i += 512) {
    int vv = binned[b0 + i];
    int d = (unsigned)vv >> 17;
    int p = atomicAdd(&hist[d], 1);
    csr[b0 + p] = vv & 0x1FFFF;            // scatter confined to ~25KB region
  }
}

// ---- CSR gather: 64-thr blocks; per-chunk VECTOR gather of dis (L2-resident),
//      per-edge v_readlane broadcasts (uniform j) + v_fmac w/ SGPR operand ----
__global__ __launch_bounds__(64) void k_gather(
    const int* __restrict__ row_start, const int* __restrict__ csr,
    const float* __restrict__ dis, const unsigned short* __restrict__ hw,
    const int* __restrict__ batch, const float* __restrict__ bgcn,
    float* __restrict__ gsum) {
  int lane = threadIdx.x;              // one wave per block
  int nb = blockIdx.x * 4;             // 25000 blocks, no tail
  float bias = bgcn[lane];
  float vout[4];
  int gid[4];
  #pragma unroll
  for (int k = 0; k < 4; ++k) {
    int n = nb + k;                    // uniform: blockIdx-derived only
    int st = row_start[n], en = row_start[n + 1];
    float dn = rsqrtf((float)(en - st + 1));   // deg + self-loop
    float a0 = 0.f, a1 = 0.f, a2 = 0.f, a3 = 0.f;
    for (int c = st; c < en; c += 64) {
      int m = min(64, en - c);         // uniform
      int idx = c + lane;
      int chunk = 0; float dv = 0.f;
      if (idx < en) { chunk = csr[idx]; dv = dis[chunk]; }   // vector gather, L2-hit
      int dvb = __float_as_int(dv);
      int j = 0;
      for (; j + 4 <= m; j += 4) {     // j uniform -> v_readlane w/ SGPR idx
        int s0 = __builtin_amdgcn_readlane(chunk, j);
        int s1 = __builtin_amdgcn_readlane(chunk, j + 1);
        int s2 = __builtin_amdgcn_readlane(chunk, j + 2);
        int s3 = __builtin_amdgcn_readlane(chunk, j + 3);
        float d0 = __int_as_float(__builtin_amdgcn_readlane(dvb, j));
        float d1 = __int_as_float(__builtin_amdgcn_readlane(dvb, j + 1));
        float d2 = __int_as_float(__builtin_amdgcn_readlane(dvb, j + 2));
        float d3 = __int_as_float(__builtin_amdgcn_readlane(dvb, j + 3));
        a0 = fmaf(d0, bf2f(hw[(size_t)s0 * 64 + lane]), a0);
        a1 = fmaf(d1, bf2f(hw[(size_t)s1 * 64 + lane]), a1);
        a2 = fmaf(d2, bf2f(hw[(size_t)s2 * 64 + lane]), a2);
        a3 = fmaf(d3, bf2f(hw[(size_t)s3 * 64 + lane]), a3);
      }
      for (; j < m; ++j) {
        int s = __builtin_amdgcn_readlane(chunk, j);
        float d = __int_as_float(__builtin_amdgcn_readlane(dvb, j));
        a0 = fmaf(d, bf2f(hw[(size_t)s * 64 + lane]), a0);
      }
    }
    float self = bf2f(hw[(size_t)n * 64 + lane]);
    float sum = (a0 + a1) + (a2 + a3);
    vout[k] = fmaxf(dn * fmaf(dn, self, sum) + bias, 0.f);   // dn*(sum + dn*self) + b
    gid[k] = batch[n];
  }
  float vs = vout[0];
  int cg = gid[0];
  #pragma unroll
  for (int k = 1; k < 4; ++k) {
    if (gid[k] == cg) vs += vout[k];
    else {
      atomicAdd(&gsum[cg * 64 + lane], vs);
      vs = vout[k]; cg = gid[k];
    }
  }
  atomicAdd(&gsum[cg * 64 + lane], vs);
}

// ---- classifier; graph count via binary search on sorted batch ----
__global__ void k_cls(const float* __restrict__ gsum, const int* __restrict__ batch,
                      const float* __restrict__ W1, const float* __restrict__ b1,
                      const float* __restrict__ W2, const float* __restrict__ b2,
                      float* __restrict__ out) {
  __shared__ float gm[64];
  __shared__ int cntS;
  int j = threadIdx.x;
  int g = blockIdx.x;
  if (j == 0) {
    int lo = 0, hi = N_NODES;
    while (lo < hi) { int mid = (lo + hi) >> 1; if (batch[mid] < g) lo = mid + 1; else hi = mid; }
    int lo2 = lo, hi2 = N_NODES;
    while (lo2 < hi2) { int mid = (lo2 + hi2) >> 1; if (batch[mid] < g + 1) lo2 = mid + 1; else hi2 = mid; }
    cntS = lo2 - lo;
  }
  __syncthreads();
  float denom = fmaxf((float)cntS, 1.0f);
  gm[j] = gsum[g * 64 + j] / denom;
  __syncthreads();
  float hid = b1[j];
  #pragma unroll
  for (int k = 0; k < 64; ++k) hid += gm[k] * W1[k * 64 + j];
  hid = fmaxf(hid, 0.f);
  float o0 = hid * W2[j * 2 + 0];
  float o1 = hid * W2[j * 2 + 1];
  #pragma unroll
  for (int off = 32; off > 0; off >>= 1) {
    o0 += __shfl_down(o0, off);
    o1 += __shfl_down(o1, off);
  }
  if (j == 0) {
    out[g * 2 + 0] = o0 + b2[0];
    out[g * 2 + 1] = o1 + b2[1];
  }
}

extern "C" void kernel_launch(void* const* d_in, const int* in_sizes, int n_in,
                              void* d_out, int out_size, void* d_ws, size_t ws_size,
                              hipStream_t stream) {
  const float* x     = (const float*)d_in[0];
  const int*   ei    = (const int*)d_in[1];
  const int*   batch = (const int*)d_in[2];
  const float* Wenc  = (const float*)d_in[3];
  const float* benc  = (const float*)d_in[4];
  const float* gamma = (const float*)d_in[5];
  const float* beta  = (const float*)d_in[6];
  const float* mean  = (const float*)d_in[7];
  const float* var   = (const float*)d_in[8];
  const float* Wgcn  = (const float*)d_in[9];
  const float* bgcn  = (const float*)d_in[10];
  const float* W1    = (const float*)d_in[11];
  const float* b1    = (const float*)d_in[12];
  const float* W2    = (const float*)d_in[13];
  const float* b2    = (const float*)d_in[14];
  float* out = (float*)d_out;

  char* ws = (char*)d_ws;
  float*          gsum      = (float*)ws;          ws += (size_t)N_GRAPHS * 64 * 4;
  int*            cnt       = (int*)ws;            ws += (size_t)NBUCK * FBLK * 4;
  int*            tot       = (int*)ws;            ws += 256 * 4;
  int*            binned    = (int*)ws;            ws += (size_t)N_EDGES * 4;
  int*            csr       = (int*)ws;            ws += (size_t)N_EDGES * 4;
  int*            row_start = (int*)ws;            ws += (size_t)(N_NODES + 32) * 4;
  float*          dis       = (float*)ws;          ws += (size_t)N_NODES * 4;
  unsigned short* hw        = (unsigned short*)ws; ws += (size_t)N_NODES * 64 * 2;

  k_cnt<<<FBLK, 256, 0, stream>>>(ei, cnt, gsum);
  k_scan_enc<<<NBUCK + ENC_BLOCKS, 256, 0, stream>>>(cnt, tot, x, Wenc, benc,
                                                     gamma, beta, mean, var, Wgcn, hw);
  k_fill<<<FBLK, 256, 0, stream>>>(ei, cnt, tot, binned);
  k_csr<<<NBUCK, 512, 0, stream>>>(tot, binned, csr, row_start, dis);
  k_gather<<<(N_NODES / 4), 64, 0, stream>>>(row_start, csr, dis, hw, batch, bgcn, gsum);
  k_cls<<<N_GRAPHS, 64, 0, stream>>>(gsum, batch, W1, b1, W2, b2, out);
}